// Round 1
// baseline (269.489 us; speedup 1.0000x reference)
//
#include <hip/hip_runtime.h>
#include <stdint.h>

#define BB 4
#define CC 256
#define NN 16384  // 128*128

typedef unsigned short u16;
typedef __attribute__((ext_vector_type(8))) __bf16 bf16x8;
typedef __attribute__((ext_vector_type(4))) float f32x4;

// fp32 -> bf16 round-to-nearest-even (bit manipulation; inputs are normal floats)
__device__ __forceinline__ u16 f2bf(float f) {
  union { float f; uint32_t u; } c;
  c.f = f;
  uint32_t u = c.u;
  return (u16)((u + 0x7fffu + ((u >> 16) & 1u)) >> 16);
}

// async global->LDS, 16 bytes per lane (global_load_lds_dwordx4)
__device__ __forceinline__ void g2l16(const u16* g, u16* l) {
  __builtin_amdgcn_global_load_lds((__attribute__((address_space(1))) void*)g,
                                   (__attribute__((address_space(3))) void*)l, 16, 0, 0);
}

// stage a 128-row x 32-col bf16 tile from row-major src (row stride `stride` elems)
// into lds[128*32]. LDS byte offset is exactly tid*16 per call (wave-uniform + lane*16).
__device__ __forceinline__ void stage128x32(const u16* src, int stride, u16* lds, int tid) {
  int r = tid >> 2;
  int c = (tid & 3) << 3;
  g2l16(src + (size_t)r * stride + c, lds + r * 32 + c);
  g2l16(src + (size_t)(r + 64) * stride + c, lds + (r + 64) * 32 + c);
}

// one BK=32 step: 4 a-frags + 4 b-frags (ds_read_b128), 16 MFMAs
__device__ __forceinline__ void mfma_tile(const u16* As, const u16* Bs, int mb, int nb,
                                          int l16, int q8, f32x4 acc[4][4]) {
  bf16x8 af[4], bf[4];
#pragma unroll
  for (int i = 0; i < 4; i++) af[i] = *(const bf16x8*)&As[(mb + i * 16 + l16) * 32 + q8];
#pragma unroll
  for (int i = 0; i < 4; i++) bf[i] = *(const bf16x8*)&Bs[(nb + i * 16 + l16) * 32 + q8];
#pragma unroll
  for (int i = 0; i < 4; i++)
#pragma unroll
    for (int j = 0; j < 4; j++)
      acc[i][j] = __builtin_amdgcn_mfma_f32_16x16x32_bf16(af[i], bf[j], acc[i][j], 0, 0, 0);
}

// x (B,C,N) fp32 -> xbT (B,N,C) bf16, 64x64 LDS tile transpose
__global__ __launch_bounds__(256) void transpose_x(const float* __restrict__ x,
                                                   u16* __restrict__ xbT) {
  __shared__ float t[64][65];
  int n0 = blockIdx.x * 64, c0 = blockIdx.y * 64, bz = blockIdx.z;
  int tid = threadIdx.x;
  int ln = tid & 63, hi = tid >> 6;
  const float* xs = x + ((size_t)bz * CC + c0) * NN + n0;
#pragma unroll
  for (int cc = hi; cc < 64; cc += 4) t[cc][ln] = xs[(size_t)cc * NN + ln];
  __syncthreads();
  u16* od = xbT + ((size_t)bz * NN + n0) * CC + c0;
#pragma unroll
  for (int nn = hi; nn < 64; nn += 4) od[(size_t)nn * CC + ln] = f2bf(t[ln][nn]);
}

// wq,wk,wv fp32 -> concatenated bf16 buffer (3*C*C elems); grid is exactly 768*256
__global__ void convert_w(const float* __restrict__ wq, const float* __restrict__ wk,
                          const float* __restrict__ wv, u16* __restrict__ wb) {
  int idx = blockIdx.x * 256 + threadIdx.x;
  const float* s = (idx < CC * CC) ? wq : ((idx < 2 * CC * CC) ? wk : wv);
  wb[idx] = f2bf(s[idx % (CC * CC)]);
}

// fused QKV projection: D[c_out][n] = sum_c w[c_out][c] * x[c][n] + bias
// A = w (M=128 tile of C, K-contig), Bt = xbT rows (n, K=c contig)
__global__ __launch_bounds__(256) void proj_kernel(
    const u16* __restrict__ wb, const u16* __restrict__ xbT,
    const float* __restrict__ bq, const float* __restrict__ bk, const float* __restrict__ bv,
    u16* __restrict__ qb, u16* __restrict__ kb, u16* __restrict__ vT) {
  __shared__ u16 As[128 * 32], Bs[128 * 32];
  int tid = threadIdx.x;
  int n0 = blockIdx.x * 128, m0 = blockIdx.y * 128;
  int z = blockIdx.z, bz = z / 3, p = z % 3;
  const u16* A = wb + p * CC * CC + (size_t)m0 * CC;
  const u16* Bt = xbT + ((size_t)bz * NN + n0) * CC;
  f32x4 acc[4][4] = {};
  int wave = tid >> 6, lane = tid & 63;
  int mb = (wave >> 1) * 64, nb = (wave & 1) * 64;
  int quad = lane >> 4, l16 = lane & 15, q8 = quad * 8;
  for (int kk = 0; kk < CC; kk += 32) {
    stage128x32(A + kk, CC, As, tid);
    stage128x32(Bt + kk, CC, Bs, tid);
    __syncthreads();
    mfma_tile(As, Bs, mb, nb, l16, q8, acc);
    __syncthreads();
  }
  const float* bias = (p == 0) ? bq : ((p == 1) ? bk : bv);
  if (p < 2) {
    // q,k stored (B,C,N) bf16: n-contiguous for the energy GEMM
    u16* o = ((p == 0) ? qb : kb) + (size_t)bz * CC * NN;
#pragma unroll
    for (int i = 0; i < 4; i++)
#pragma unroll
      for (int r = 0; r < 4; r++) {
        int cg = m0 + mb + i * 16 + quad * 4 + r;
        float bi = bias[cg];
#pragma unroll
        for (int j = 0; j < 4; j++) {
          int ng = n0 + nb + j * 16 + l16;
          o[(size_t)cg * NN + ng] = f2bf(acc[i][j][r] + bi);
        }
      }
  } else {
    // v stored transposed (B,N,C) bf16: d-contiguous for the out GEMM; 4 bf16 = 8B packed store
#pragma unroll
    for (int i = 0; i < 4; i++) {
      int cb = m0 + mb + i * 16 + quad * 4;
      float b0 = bias[cb], b1 = bias[cb + 1], b2 = bias[cb + 2], b3 = bias[cb + 3];
#pragma unroll
      for (int j = 0; j < 4; j++) {
        int ng = n0 + nb + j * 16 + l16;
        union { u16 h[4]; uint2 v; } pk;
        pk.h[0] = f2bf(acc[i][j][0] + b0);
        pk.h[1] = f2bf(acc[i][j][1] + b1);
        pk.h[2] = f2bf(acc[i][j][2] + b2);
        pk.h[3] = f2bf(acc[i][j][3] + b3);
        *(uint2*)&vT[((size_t)bz * NN + ng) * CC + cb] = pk.v;
      }
    }
  }
}

// energy[b][c][d] += sum_{n in slice} q[c][n]*k[d][n]  (split-K=32 slices of 512, fp32 atomics)
__global__ __launch_bounds__(256) void energy_kernel(const u16* __restrict__ qb,
                                                     const u16* __restrict__ kb,
                                                     float* __restrict__ en) {
  __shared__ u16 As[128 * 32], Bs[128 * 32];
  int tid = threadIdx.x;
  int c0 = (blockIdx.x >> 1) * 128, d0 = (blockIdx.x & 1) * 128;
  int s = blockIdx.y, bz = blockIdx.z;
  const u16* A = qb + ((size_t)bz * CC + c0) * NN + s * 512;
  const u16* Bt = kb + ((size_t)bz * CC + d0) * NN + s * 512;
  f32x4 acc[4][4] = {};
  int wave = tid >> 6, lane = tid & 63;
  int mb = (wave >> 1) * 64, nb = (wave & 1) * 64;
  int quad = lane >> 4, l16 = lane & 15, q8 = quad * 8;
  for (int kk = 0; kk < 512; kk += 32) {
    stage128x32(A + kk, NN, As, tid);
    stage128x32(Bt + kk, NN, Bs, tid);
    __syncthreads();
    mfma_tile(As, Bs, mb, nb, l16, q8, acc);
    __syncthreads();
  }
  float* e = en + (size_t)bz * CC * CC;
#pragma unroll
  for (int i = 0; i < 4; i++)
#pragma unroll
    for (int j = 0; j < 4; j++)
#pragma unroll
      for (int r = 0; r < 4; r++)
        atomicAdd(&e[(size_t)(c0 + mb + i * 16 + quad * 4 + r) * CC + d0 + nb + j * 16 + l16],
                  acc[i][j][r]);
}

// softmax over d (256) with 1/sqrt(N)=1/128 scale; output bf16
__global__ __launch_bounds__(256) void softmax_kernel(const float* __restrict__ en,
                                                      u16* __restrict__ att) {
  int row = blockIdx.x;  // bz*C + c
  int t = threadIdx.x;
  __shared__ float red[256];
  float v = en[(size_t)row * CC + t] * 0.0078125f;
  red[t] = v;
  __syncthreads();
  for (int s = 128; s > 0; s >>= 1) {
    if (t < s) red[t] = fmaxf(red[t], red[t + s]);
    __syncthreads();
  }
  float m = red[0];
  __syncthreads();
  float e = __expf(v - m);
  red[t] = e;
  __syncthreads();
  for (int s = 128; s > 0; s >>= 1) {
    if (t < s) red[t] += red[t + s];
    __syncthreads();
  }
  float inv = 1.0f / red[0];
  att[(size_t)row * CC + t] = f2bf(e * inv);
}

// out[b][c][n] = sum_d att[c][d] * v[d][n] + x[b][c][n]
// A = att rows (d-contig), Bt = vT rows (d-contig)
__global__ __launch_bounds__(256) void out_kernel(const u16* __restrict__ att,
                                                  const u16* __restrict__ vT,
                                                  const float* __restrict__ x,
                                                  float* __restrict__ out) {
  __shared__ u16 As[128 * 32], Bs[128 * 32];
  int tid = threadIdx.x;
  int n0 = blockIdx.x * 128, m0 = blockIdx.y * 128, bz = blockIdx.z;
  const u16* A = att + ((size_t)bz * CC + m0) * CC;
  const u16* Bt = vT + ((size_t)bz * NN + n0) * CC;
  f32x4 acc[4][4] = {};
  int wave = tid >> 6, lane = tid & 63;
  int mb = (wave >> 1) * 64, nb = (wave & 1) * 64;
  int quad = lane >> 4, l16 = lane & 15, q8 = quad * 8;
  for (int kk = 0; kk < CC; kk += 32) {
    stage128x32(A + kk, CC, As, tid);
    stage128x32(Bt + kk, CC, Bs, tid);
    __syncthreads();
    mfma_tile(As, Bs, mb, nb, l16, q8, acc);
    __syncthreads();
  }
#pragma unroll
  for (int i = 0; i < 4; i++)
#pragma unroll
    for (int r = 0; r < 4; r++) {
      int cg = m0 + mb + i * 16 + quad * 4 + r;
#pragma unroll
      for (int j = 0; j < 4; j++) {
        int ng = n0 + nb + j * 16 + l16;
        size_t idx = ((size_t)bz * CC + cg) * NN + ng;
        out[idx] = acc[i][j][r] + x[idx];
      }
    }
}

extern "C" void kernel_launch(void* const* d_in, const int* in_sizes, int n_in,
                              void* d_out, int out_size, void* d_ws, size_t ws_size,
                              hipStream_t stream) {
  (void)in_sizes; (void)n_in; (void)out_size; (void)ws_size;
  const float* x = (const float*)d_in[0];
  const float* wq = (const float*)d_in[1];
  const float* bq = (const float*)d_in[2];
  const float* wk = (const float*)d_in[3];
  const float* bk = (const float*)d_in[4];
  const float* wv = (const float*)d_in[5];
  const float* bv = (const float*)d_in[6];
  float* out = (float*)d_out;

  char* ws = (char*)d_ws;
  // workspace layout (bytes): total ~136.2 MB
  u16* xbT = (u16*)(ws + 0);            // B*N*C bf16 = 32 MiB
  u16* qb  = (u16*)(ws + 33554432);     // B*C*N bf16 = 32 MiB
  u16* kb  = (u16*)(ws + 67108864);     // 32 MiB
  u16* vT  = (u16*)(ws + 100663296);    // B*N*C bf16 = 32 MiB
  float* en = (float*)(ws + 134217728); // B*C*C fp32 = 1 MiB
  u16* att = (u16*)(ws + 135266304);    // B*C*C bf16 = 0.5 MiB
  u16* wb  = (u16*)(ws + 135790592);    // 3*C*C bf16 = 384 KiB

  transpose_x<<<dim3(NN / 64, CC / 64, BB), 256, 0, stream>>>(x, xbT);
  convert_w<<<768, 256, 0, stream>>>(wq, wk, wv, wb);
  hipMemsetAsync(en, 0, (size_t)BB * CC * CC * sizeof(float), stream);
  proj_kernel<<<dim3(NN / 128, CC / 128, BB * 3), 256, 0, stream>>>(wb, xbT, bq, bk, bv, qb, kb, vT);
  energy_kernel<<<dim3(4, 32, BB), 256, 0, stream>>>(qb, kb, en);
  softmax_kernel<<<BB * CC, 256, 0, stream>>>(en, att);
  out_kernel<<<dim3(NN / 128, CC / 128, BB), 256, 0, stream>>>(att, vT, x, out);
}

// Round 2
// 268.906 us; speedup vs baseline: 1.0022x; 1.0022x over previous
//
#include <hip/hip_runtime.h>
#include <stdint.h>

#define BB 4
#define CC 256
#define NN 16384  // 128*128

typedef unsigned short u16;
typedef __attribute__((ext_vector_type(8))) __bf16 bf16x8;
typedef __attribute__((ext_vector_type(4))) float f32x4;

// fp32 -> bf16 round-to-nearest-even
__device__ __forceinline__ u16 f2bf(float f) {
  union { float f; uint32_t u; } c;
  c.f = f;
  uint32_t u = c.u;
  return (u16)((u + 0x7fffu + ((u >> 16) & 1u)) >> 16);
}

// async global->LDS, 16 bytes per lane (global_load_lds_dwordx4)
__device__ __forceinline__ void g2l16(const u16* g, u16* l) {
  __builtin_amdgcn_global_load_lds((__attribute__((address_space(1))) void*)g,
                                   (__attribute__((address_space(3))) void*)l, 16, 0, 0);
}

// stage 128x32 bf16 tile (row stride `stride` elems) into lds[128*32]
__device__ __forceinline__ void stage128x32(const u16* src, int stride, u16* lds, int tid) {
  int r = tid >> 2;
  int c = (tid & 3) << 3;
  g2l16(src + (size_t)r * stride + c, lds + r * 32 + c);
  g2l16(src + (size_t)(r + 64) * stride + c, lds + (r + 64) * 32 + c);
}

// one BK=32 step: 16 MFMAs on 128x128 tile (4 waves, each 64x64)
__device__ __forceinline__ void mfma_tile(const u16* As, const u16* Bs, int mb, int nb,
                                          int l16, int q8, f32x4 acc[4][4]) {
  bf16x8 af[4], bf[4];
#pragma unroll
  for (int i = 0; i < 4; i++) af[i] = *(const bf16x8*)&As[(mb + i * 16 + l16) * 32 + q8];
#pragma unroll
  for (int i = 0; i < 4; i++) bf[i] = *(const bf16x8*)&Bs[(nb + i * 16 + l16) * 32 + q8];
#pragma unroll
  for (int i = 0; i < 4; i++)
#pragma unroll
    for (int j = 0; j < 4; j++)
      acc[i][j] = __builtin_amdgcn_mfma_f32_16x16x32_bf16(af[i], bf[j], acc[i][j], 0, 0, 0);
}

// prep: x fp32 (B,C,N) -> xb bf16 (B,C,N), xbT bf16 (B,N,C), s[b][c] = row sums
__global__ __launch_bounds__(256) void prep_kernel(const float* __restrict__ x,
                                                   u16* __restrict__ xb,
                                                   u16* __restrict__ xbT,
                                                   float* __restrict__ s) {
  __shared__ float t[64][65];
  __shared__ float rs[64][4];
  int n0 = blockIdx.x * 64, c0 = blockIdx.y * 64, bz = blockIdx.z;
  int tid = threadIdx.x, ln = tid & 63, hi = tid >> 6;
  const float* xs = x + ((size_t)bz * CC + c0) * NN + n0;
  u16* xbp = xb + ((size_t)bz * CC + c0) * NN + n0;
#pragma unroll
  for (int cc = hi; cc < 64; cc += 4) {
    float v = xs[(size_t)cc * NN + ln];
    t[cc][ln] = v;
    xbp[(size_t)cc * NN + ln] = f2bf(v);
  }
  __syncthreads();
  {
    int r = tid >> 2, q = tid & 3;
    float p = 0.f;
#pragma unroll
    for (int i = 0; i < 16; i++) p += t[r][q * 16 + i];
    rs[r][q] = p;
  }
  u16* od = xbT + ((size_t)bz * NN + n0) * CC + c0;
#pragma unroll
  for (int nn = hi; nn < 64; nn += 4) od[(size_t)nn * CC + ln] = f2bf(t[ln][nn]);
  __syncthreads();
  if (tid < 64)
    atomicAdd(&s[bz * CC + c0 + tid], rs[tid][0] + rs[tid][1] + rs[tid][2] + rs[tid][3]);
}

// G[b] = xb[b] xb[b]^T  (C x C fp32, split-K=32 slices of 512, atomics)
__global__ __launch_bounds__(256) void gram_kernel(const u16* __restrict__ xb,
                                                   float* __restrict__ G) {
  __shared__ u16 As[128 * 32], Bs[128 * 32];
  int tid = threadIdx.x;
  int c0 = (blockIdx.x >> 1) * 128, d0 = (blockIdx.x & 1) * 128;
  int sl = blockIdx.y, bz = blockIdx.z;
  const u16* A = xb + ((size_t)bz * CC + c0) * NN + sl * 512;
  const u16* Bt = xb + ((size_t)bz * CC + d0) * NN + sl * 512;
  f32x4 acc[4][4] = {};
  int wave = tid >> 6, lane = tid & 63;
  int mb = (wave >> 1) * 64, nb = (wave & 1) * 64;
  int quad = lane >> 4, l16 = lane & 15, q8 = quad * 8;
  for (int kk = 0; kk < 512; kk += 32) {
    stage128x32(A + kk, NN, As, tid);
    stage128x32(Bt + kk, NN, Bs, tid);
    __syncthreads();
    mfma_tile(As, Bs, mb, nb, l16, q8, acc);
    __syncthreads();
  }
  float* g = G + (size_t)bz * CC * CC;
#pragma unroll
  for (int i = 0; i < 4; i++)
#pragma unroll
    for (int j = 0; j < 4; j++)
#pragma unroll
      for (int r = 0; r < 4; r++)
        atomicAdd(&g[(size_t)(c0 + mb + i * 16 + quad * 4 + r) * CC + d0 + nb + j * 16 + l16],
                  acc[i][j][r]);
}

// u[b][o] = Wq[o,:].s[b]; w[b][p] = Wk[p,:].s[b]
__global__ __launch_bounds__(256) void uw_kernel(const float* __restrict__ Wq,
                                                 const float* __restrict__ Wk,
                                                 const float* __restrict__ s,
                                                 float* __restrict__ u, float* __restrict__ w) {
  __shared__ float ss[CC];
  int which = blockIdx.x, b = blockIdx.y, t = threadIdx.x;
  ss[t] = s[b * CC + t];
  __syncthreads();
  const float* W = which ? Wk : Wq;
  const float4* row = (const float4*)&W[(size_t)t * CC];
  float acc = 0.f;
#pragma unroll 4
  for (int c = 0; c < CC / 4; c++) {
    float4 v = row[c];
    acc += v.x * ss[c * 4] + v.y * ss[c * 4 + 1] + v.z * ss[c * 4 + 2] + v.w * ss[c * 4 + 3];
  }
  (which ? w : u)[b * CC + t] = acc;
}

// T[b][p][c] = sum_d Wk[p][d] G[b][d][c]   (fp32 NN GEMM, 32x32 tiles)
__global__ __launch_bounds__(256) void nn_T_kernel(const float* __restrict__ Wk,
                                                   const float* __restrict__ G,
                                                   float* __restrict__ T) {
  __shared__ float As[32][33], Bs2[32][33];
  int t = threadIdx.x;
  int c0 = blockIdx.x * 32, p0 = blockIdx.y * 32, b = blockIdx.z;
  const float* Ap = Wk + (size_t)p0 * CC;
  const float* Bp = G + (size_t)b * CC * CC + c0;
  float acc[2][2] = {};
  int r = t >> 3, c4 = (t & 7) * 4;
  int tr = t >> 4, tc = t & 15;
  for (int kk = 0; kk < CC; kk += 32) {
    float4 av = *(const float4*)&Ap[(size_t)r * CC + kk + c4];
    float4 bv = *(const float4*)&Bp[(size_t)(kk + r) * CC + c4];
    As[r][c4] = av.x; As[r][c4 + 1] = av.y; As[r][c4 + 2] = av.z; As[r][c4 + 3] = av.w;
    Bs2[r][c4] = bv.x; Bs2[r][c4 + 1] = bv.y; Bs2[r][c4 + 2] = bv.z; Bs2[r][c4 + 3] = bv.w;
    __syncthreads();
#pragma unroll
    for (int k = 0; k < 32; k++) {
      float a0 = As[tr * 2][k], a1 = As[tr * 2 + 1][k];
      float b0 = Bs2[k][tc * 2], b1 = Bs2[k][tc * 2 + 1];
      acc[0][0] += a0 * b0; acc[0][1] += a0 * b1;
      acc[1][0] += a1 * b0; acc[1][1] += a1 * b1;
    }
    __syncthreads();
  }
#pragma unroll
  for (int i = 0; i < 2; i++)
#pragma unroll
    for (int j = 0; j < 2; j++)
      T[(size_t)b * CC * CC + (size_t)(p0 + tr * 2 + i) * CC + c0 + tc * 2 + j] = acc[i][j];
}

// E[b][o][p] = (sum_c Wq[o][c] T[b][p][c] + u[o]bk[p] + bq[o]w[p] + N bq[o]bk[p]) / 128
__global__ __launch_bounds__(256) void nt_E_kernel(const float* __restrict__ Wq,
                                                   const float* __restrict__ T,
                                                   const float* __restrict__ u,
                                                   const float* __restrict__ w,
                                                   const float* __restrict__ bq,
                                                   const float* __restrict__ bk,
                                                   float* __restrict__ E) {
  __shared__ float As[32][33], Bs2[32][33];
  int t = threadIdx.x;
  int p0 = blockIdx.x * 32, o0 = blockIdx.y * 32, b = blockIdx.z;
  const float* Ap = Wq + (size_t)o0 * CC;
  const float* Bp = T + (size_t)b * CC * CC + (size_t)p0 * CC;
  float acc[2][2] = {};
  int r = t >> 3, c4 = (t & 7) * 4;
  int tr = t >> 4, tc = t & 15;
  for (int kk = 0; kk < CC; kk += 32) {
    float4 av = *(const float4*)&Ap[(size_t)r * CC + kk + c4];
    float4 bv = *(const float4*)&Bp[(size_t)r * CC + kk + c4];
    As[r][c4] = av.x; As[r][c4 + 1] = av.y; As[r][c4 + 2] = av.z; As[r][c4 + 3] = av.w;
    Bs2[r][c4] = bv.x; Bs2[r][c4 + 1] = bv.y; Bs2[r][c4 + 2] = bv.z; Bs2[r][c4 + 3] = bv.w;
    __syncthreads();
#pragma unroll
    for (int k = 0; k < 32; k++) {
      float a0 = As[tr * 2][k], a1 = As[tr * 2 + 1][k];
      float b0 = Bs2[tc * 2][k], b1 = Bs2[tc * 2 + 1][k];
      acc[0][0] += a0 * b0; acc[0][1] += a0 * b1;
      acc[1][0] += a1 * b0; acc[1][1] += a1 * b1;
    }
    __syncthreads();
  }
#pragma unroll
  for (int i = 0; i < 2; i++)
#pragma unroll
    for (int j = 0; j < 2; j++) {
      int o = o0 + tr * 2 + i, p = p0 + tc * 2 + j;
      float e = acc[i][j] + u[b * CC + o] * bk[p] + bq[o] * w[b * CC + p] +
                16384.0f * bq[o] * bk[p];
      E[(size_t)b * CC * CC + (size_t)o * CC + p] = e * 0.0078125f;
    }
}

// softmax over p (input already scaled), fp32 out
__global__ __launch_bounds__(256) void softmax_kernel(const float* __restrict__ E,
                                                      float* __restrict__ att) {
  int row = blockIdx.x;
  int t = threadIdx.x;
  __shared__ float red[256];
  float v = E[(size_t)row * CC + t];
  red[t] = v;
  __syncthreads();
  for (int s2 = 128; s2 > 0; s2 >>= 1) {
    if (t < s2) red[t] = fmaxf(red[t], red[t + s2]);
    __syncthreads();
  }
  float m = red[0];
  __syncthreads();
  float e = __expf(v - m);
  red[t] = e;
  __syncthreads();
  for (int s2 = 128; s2 > 0; s2 >>= 1) {
    if (t < s2) red[t] += red[t + s2];
    __syncthreads();
  }
  att[(size_t)row * CC + t] = e / red[0];
}

// Mv[b][o][c'] = sum_d att[b][o][d] Wv[d][c']  -> bf16
__global__ __launch_bounds__(256) void nn_Mv_kernel(const float* __restrict__ att,
                                                    const float* __restrict__ Wv,
                                                    u16* __restrict__ Mvb) {
  __shared__ float As[32][33], Bs2[32][33];
  int t = threadIdx.x;
  int c0 = blockIdx.x * 32, o0 = blockIdx.y * 32, b = blockIdx.z;
  const float* Ap = att + (size_t)b * CC * CC + (size_t)o0 * CC;
  const float* Bp = Wv + c0;
  float acc[2][2] = {};
  int r = t >> 3, c4 = (t & 7) * 4;
  int tr = t >> 4, tc = t & 15;
  for (int kk = 0; kk < CC; kk += 32) {
    float4 av = *(const float4*)&Ap[(size_t)r * CC + kk + c4];
    float4 bv = *(const float4*)&Bp[(size_t)(kk + r) * CC + c4];
    As[r][c4] = av.x; As[r][c4 + 1] = av.y; As[r][c4 + 2] = av.z; As[r][c4 + 3] = av.w;
    Bs2[r][c4] = bv.x; Bs2[r][c4 + 1] = bv.y; Bs2[r][c4 + 2] = bv.z; Bs2[r][c4 + 3] = bv.w;
    __syncthreads();
#pragma unroll
    for (int k = 0; k < 32; k++) {
      float a0 = As[tr * 2][k], a1 = As[tr * 2 + 1][k];
      float b0 = Bs2[k][tc * 2], b1 = Bs2[k][tc * 2 + 1];
      acc[0][0] += a0 * b0; acc[0][1] += a0 * b1;
      acc[1][0] += a1 * b0; acc[1][1] += a1 * b1;
    }
    __syncthreads();
  }
#pragma unroll
  for (int i = 0; i < 2; i++)
#pragma unroll
    for (int j = 0; j < 2; j++)
      Mvb[(size_t)b * CC * CC + (size_t)(o0 + tr * 2 + i) * CC + c0 + tc * 2 + j] =
          f2bf(acc[i][j]);
}

// bo[b][o] = att[b][o][:] . bv
__global__ __launch_bounds__(256) void bo_kernel(const float* __restrict__ att,
                                                 const float* __restrict__ bv,
                                                 float* __restrict__ bo) {
  __shared__ float bs[CC];
  int b = blockIdx.x, t = threadIdx.x;
  bs[t] = bv[t];
  __syncthreads();
  const float4* row = (const float4*)&att[(size_t)b * CC * CC + (size_t)t * CC];
  float acc = 0.f;
#pragma unroll 4
  for (int d = 0; d < CC / 4; d++) {
    float4 v = row[d];
    acc += v.x * bs[d * 4] + v.y * bs[d * 4 + 1] + v.z * bs[d * 4 + 2] + v.w * bs[d * 4 + 3];
  }
  bo[b * CC + t] = acc;
}

// out[b][c][n] = sum_c' Mv[c][c'] x[c'][n] + bo[c] + x[c][n]
__global__ __launch_bounds__(256) void out_kernel(const u16* __restrict__ Mvb,
                                                  const u16* __restrict__ xbT,
                                                  const float* __restrict__ bo,
                                                  const float* __restrict__ x,
                                                  float* __restrict__ out) {
  __shared__ u16 As[128 * 32], Bs[128 * 32];
  int tid = threadIdx.x;
  int n0 = blockIdx.x * 128, m0 = blockIdx.y * 128, bz = blockIdx.z;
  const u16* A = Mvb + (size_t)bz * CC * CC + (size_t)m0 * CC;
  const u16* Bt = xbT + ((size_t)bz * NN + n0) * CC;
  f32x4 acc[4][4] = {};
  int wave = tid >> 6, lane = tid & 63;
  int mb = (wave >> 1) * 64, nb = (wave & 1) * 64;
  int quad = lane >> 4, l16 = lane & 15, q8 = quad * 8;
  for (int kk = 0; kk < CC; kk += 32) {
    stage128x32(A + kk, CC, As, tid);
    stage128x32(Bt + kk, CC, Bs, tid);
    __syncthreads();
    mfma_tile(As, Bs, mb, nb, l16, q8, acc);
    __syncthreads();
  }
#pragma unroll
  for (int i = 0; i < 4; i++)
#pragma unroll
    for (int r = 0; r < 4; r++) {
      int cg = m0 + mb + i * 16 + quad * 4 + r;
      float bc = bo[bz * CC + cg];
#pragma unroll
      for (int j = 0; j < 4; j++) {
        int ng = n0 + nb + j * 16 + l16;
        size_t idx = ((size_t)bz * CC + cg) * NN + ng;
        out[idx] = acc[i][j][r] + bc + x[idx];
      }
    }
}

extern "C" void kernel_launch(void* const* d_in, const int* in_sizes, int n_in,
                              void* d_out, int out_size, void* d_ws, size_t ws_size,
                              hipStream_t stream) {
  (void)in_sizes; (void)n_in; (void)out_size; (void)ws_size;
  const float* x = (const float*)d_in[0];
  const float* wq = (const float*)d_in[1];
  const float* bq = (const float*)d_in[2];
  const float* wk = (const float*)d_in[3];
  const float* bk = (const float*)d_in[4];
  const float* wv = (const float*)d_in[5];
  const float* bv = (const float*)d_in[6];
  float* out = (float*)d_out;

  char* ws = (char*)d_ws;
  u16* xb   = (u16*)(ws + 0);           // 32 MiB  (B,C,N) bf16
  u16* xbT  = (u16*)(ws + 33554432);    // 32 MiB  (B,N,C) bf16
  float* G  = (float*)(ws + 67108864);  // 1 MiB   (B,C,C) fp32
  float* s  = (float*)(ws + 68157440);  // 4 KiB   (B,C)   fp32  (adjacent to G for one memset)
  float* T  = (float*)(ws + 68161536);  // 1 MiB
  float* E  = (float*)(ws + 69210112);  // 1 MiB
  float* att = (float*)(ws + 70258688); // 1 MiB
  float* u  = (float*)(ws + 71307264);  // 4 KiB
  float* w  = (float*)(ws + 71311360);  // 4 KiB
  u16* Mvb  = (u16*)(ws + 71315456);    // 512 KiB
  float* bo = (float*)(ws + 71839744);  // 4 KiB

  // zero G + s (adjacent region) before the atomic accumulators run
  hipMemsetAsync(G, 0, 1048576 + 4096, stream);
  prep_kernel<<<dim3(NN / 64, CC / 64, BB), 256, 0, stream>>>(x, xb, xbT, s);
  gram_kernel<<<dim3(4, 32, BB), 256, 0, stream>>>(xb, G);
  uw_kernel<<<dim3(2, BB), 256, 0, stream>>>(wq, wk, s, u, w);
  nn_T_kernel<<<dim3(8, 8, BB), 256, 0, stream>>>(wk, G, T);
  nt_E_kernel<<<dim3(8, 8, BB), 256, 0, stream>>>(wq, T, u, w, bq, bk, E);
  softmax_kernel<<<BB * CC, 256, 0, stream>>>(E, att);
  nn_Mv_kernel<<<dim3(8, 8, BB), 256, 0, stream>>>(att, wv, Mvb);
  bo_kernel<<<BB, 256, 0, stream>>>(att, bv, bo);
  out_kernel<<<dim3(NN / 128, CC / 128, BB), 256, 0, stream>>>(Mvb, xbT, bo, x, out);
}